// Round 16
// baseline (97.942 us; speedup 1.0000x reference)
//
#include <hip/hip_runtime.h>

constexpr int Bb = 8;     // batch
constexpr int Nn = 1024;  // nodes
constexpr int Cc = 256;   // channels
constexpr int Hh = 4;     // heads
constexpr int WROW = 2 * Cc + 4;  // 516, same for W1 and W2

typedef float fx4 __attribute__((ext_vector_type(4)));
typedef float f32x4 __attribute__((ext_vector_type(4)));
typedef __bf16 bf16x8 __attribute__((ext_vector_type(8)));

#define GLL16(src, dst)                                                      \
  __builtin_amdgcn_global_load_lds(                                          \
      (const __attribute__((address_space(1))) void*)(src),                  \
      (__attribute__((address_space(3))) void*)(dst), 16, 0, 0)

// ---------------------------------------------------------------------------
// roipack v2 (r13-proven, bit-identical output).
// grid 2048, block 256 (4 rows/block).
// ---------------------------------------------------------------------------
__global__ __launch_bounds__(256) void k_roipack2(const float* __restrict__ roi,
                                                  const float* __restrict__ sm,
                                                  unsigned long long* __restrict__ roib,
                                                  int* __restrict__ cntb) {
  __shared__ short jmapS[1024];
  __shared__ unsigned char m4S[4][256];
  __shared__ int cntS;
  const int t = threadIdx.x, w = t >> 6, l = t & 63;
  const int gid = blockIdx.x * 4 + w;
  const int b = gid >> 10;

  if (w == 0) {
    int base = 0;
#pragma unroll
    for (int jc = 0; jc < 16; ++jc) {
      const int j = jc * 64 + l;
      const bool act = sm[b * Nn + j] != 0.f;
      const unsigned long long m = __ballot(act);
      if (act) jmapS[base + __popcll(m & ((1ull << l) - 1))] = (short)j;
      base += __popcll(m);
    }
    if (l == 0) {
      cntS = base;
      if ((blockIdx.x & 255) == 0) cntb[b] = base;
    }
  }
  {
    const fx4* r4 = (const fx4*)(roi + (size_t)gid * Nn);
#pragma unroll
    for (int k = 0; k < 4; ++k) {
      fx4 v = r4[k * 64 + l];
      unsigned nb = (v[0] != 0.f ? 1u : 0u) | (v[1] != 0.f ? 2u : 0u) |
                    (v[2] != 0.f ? 4u : 0u) | (v[3] != 0.f ? 8u : 0u);
      m4S[w][k * 64 + l] = (unsigned char)nb;
    }
  }
  __syncthreads();
  const int cnt = cntS;
  unsigned long long* orow = roib + (size_t)gid * 16;
#pragma unroll 4
  for (int pc = 0; pc < 16; ++pc) {
    const int idx = pc * 64 + l;
    const bool valid = idx < cnt;
    const int j = valid ? (int)jmapS[idx] : 0;
    const bool bit = valid && ((m4S[w][j >> 2] >> (j & 3)) & 1);
    unsigned long long m = __ballot(bit);
    if (l == 0) orow[pc] = m;
  }
}

// ---------------------------------------------------------------------------
// Grouped 1x1 conv (MFMA) + ReLU + fused qt/kt projection (r15).
// src is ALWAYS [B,N,C] row-major. grid (8 b, 32 node-tiles), block 256.
// ---------------------------------------------------------------------------
__global__ __launch_bounds__(256) void k_gconvq(const float* __restrict__ src,
                                                const float* __restrict__ cw,
                                                const float* __restrict__ cb,
                                                const float* __restrict__ sm,
                                                const float* __restrict__ spat,
                                                const float* __restrict__ W,
                                                const float* __restrict__ bias,
                                                float* __restrict__ out,
                                                __bf16* __restrict__ gsm,
                                                float* __restrict__ qt,
                                                float* __restrict__ kt) {
  __shared__ __align__(16) bf16x8 xsB[32][32];  // [node][c-chunk^swz] 16KB
  __shared__ __align__(16) float WqkS[8][256];  // rows h*2+{q,k}, 8KB
  __shared__ float cbS[256];
  __shared__ float smS[32];
  __shared__ int pcolS[32];
  __shared__ int actS[32];
  const int b = blockIdx.x, tile = blockIdx.y;
  const int n0 = tile * 32;
  const int t = threadIdx.x, w = t >> 6, l = t & 63;

  if (w == 0) {
    const int fullc = n0 >> 6;
    int cbase = 0;
    unsigned long long am = 0;
    for (int jc = 0; jc <= fullc; ++jc) {
      unsigned long long m = __ballot(sm[b * Nn + jc * 64 + l] != 0.f);
      if (jc < fullc) cbase += __popcll(m); else am = m;
    }
    const int lsel = l - (n0 & 63);
    if (lsel >= 0 && lsel < 32) {
      pcolS[lsel] = cbase + __popcll(am & ((1ull << l) - 1));
      actS[lsel] = (int)((am >> l) & 1);
      smS[lsel] = 0.25f * sm[b * Nn + n0 + lsel];
    }
  }
  cbS[t] = cb[t];
  for (int idx = t; idx < 2048; idx += 256) {
    const int row = idx >> 8, c = idx & 255;
    WqkS[row][c] = W[(row >> 1) * WROW + (row & 1) * Cc + c];
  }

  {
    const int n = t >> 3, c0 = (t & 7) * 32;
    const float* srow = src + ((size_t)(b * Nn + n0 + n)) * Cc + c0;
#pragma unroll
    for (int k = 0; k < 4; ++k) {
      fx4 v0 = *(const fx4*)&srow[k * 8];
      fx4 v1 = *(const fx4*)&srow[k * 8 + 4];
      bf16x8 bv;
#pragma unroll
      for (int e = 0; e < 4; ++e) { bv[e] = (__bf16)v0[e]; bv[4 + e] = (__bf16)v1[e]; }
      xsB[n][((c0 >> 3) + k) ^ (n & 7)] = bv;
    }
  }

  const int g = w, dl = l & 15, q = l >> 4;

  bf16x8 a[4][2];
#pragma unroll
  for (int of = 0; of < 4; ++of)
#pragma unroll
    for (int ks = 0; ks < 2; ++ks) {
      const float* cwp = cw + ((size_t)(g * 64 + of * 16 + dl)) * 64 + ks * 32 + q * 8;
      fx4 c0 = *(const fx4*)cwp;
      fx4 c1 = *(const fx4*)(cwp + 4);
#pragma unroll
      for (int e = 0; e < 4; ++e) { a[of][ks][e] = (__bf16)c0[e]; a[of][ks][4 + e] = (__bf16)c1[e]; }
    }
  __syncthreads();

  f32x4 acc[4][2] = {};
#pragma unroll
  for (int nf = 0; nf < 2; ++nf) {
    const int n = nf * 16 + dl;
#pragma unroll
    for (int ks = 0; ks < 2; ++ks) {
      bf16x8 bv = xsB[n][(g * 8 + ks * 4 + q) ^ (n & 7)];
#pragma unroll
      for (int of = 0; of < 4; ++of)
        acc[of][nf] = __builtin_amdgcn_mfma_f32_16x16x32_bf16(a[of][ks], bv, acc[of][nf], 0, 0, 0);
    }
  }
#pragma unroll
  for (int of = 0; of < 4; ++of)
#pragma unroll
    for (int nf = 0; nf < 2; ++nf) {
      const int n = nf * 16 + dl;
      const float smv = smS[n];
      const int act = actS[n];
      const int pc = pcolS[n];
#pragma unroll
      for (int r = 0; r < 4; ++r) {
        const int co = g * 64 + of * 16 + 4 * q + r;
        const float val = fmaxf(acc[of][nf][r] + cbS[co], 0.f);
        const size_t orow = ((size_t)(b * Cc + co)) * Nn;
        out[orow + n0 + n] = val;
        if (act) gsm[orow + pc] = (__bf16)(smv * val);
      }
    }

  {
    const int nl = l & 31, half = l >> 5;
    float qa = 0.f, ka = 0.f;
#pragma unroll
    for (int k = 0; k < 16; ++k) {
      bf16x8 bv = xsB[nl][(half * 16 + k) ^ (nl & 7)];
      const float* wqp = &WqkS[g * 2 + 0][half * 128 + k * 8];
      const float* wkp = &WqkS[g * 2 + 1][half * 128 + k * 8];
#pragma unroll
      for (int e = 0; e < 8; ++e) {
        const float x = (float)bv[e];
        qa = fmaf(x, wqp[e], qa);
        ka = fmaf(x, wkp[e], ka);
      }
    }
    qa += __shfl_xor(qa, 32, 64);
    ka += __shfl_xor(ka, 32, 64);
    if (l < 32) {
      const int n = n0 + nl;
      const float s0 = spat[(b * Nn + n) * 2 + 0];
      const float s1 = spat[(b * Nn + n) * 2 + 1];
      const float* wsp = W + g * WROW + 2 * Cc;
      const float qf = qa + s0 * wsp[0] + s1 * wsp[1] + bias[g];
      const float kf = ka + s0 * wsp[2] + s1 * wsp[3];
      kt[(b * Hh + g) * Nn + n] = kf * -1.44269504f;
      if (actS[nl]) qt[(b * Hh + g) * Nn + pcolS[nl]] = qf * -1.44269504f;
    }
  }
}

// ---------------------------------------------------------------------------
// MFMA fused attention apply, v8 = r15 v7 + (MODE 1 only) fused LayerNorm
// via the split-K last-block-finisher pattern:
//   - 4 head-blocks share each (b,it); after epilogue stores every block does
//     __syncthreads (drains stores to L2: compiler emits vmcnt(0) before
//     s_barrier), then t0 does __threadfence + atomicAdd(lncnt[b*16+it]).
//   - The block seeing old==3 LNs its 64 rows: all 4 heads' channels are in
//     the same-XCD L2 (blockIdx.x == b keeps a batch on one XCD) and occupy
//     disjoint 64B lines per head, so the finisher's L1 holds no stale copy.
//   - LN math copied verbatim from the old k_lnfinal (same reduce order).
//   - gt residual tile staged into the drained GLL ring LDS (49KB >= 33KB;
//     all GLLs landed at the post-loop __syncthreads).
// lncnt zeroed per call by hipMemsetAsync (capture-safe).
// grid dim3(8 b, 16 it, 4 h): linear%8 == b -> each XCD serves one batch.
// ---------------------------------------------------------------------------
template <int MODE>
__global__ __launch_bounds__(512, 4) void k_apply7(const float* __restrict__ g,
                                                   const __bf16* __restrict__ gsm,
                                                   const float* __restrict__ qt,
                                                   const float* __restrict__ kt,
                                                   const unsigned char* __restrict__ roib,
                                                   const float* __restrict__ sm,
                                                   const int* __restrict__ cntb,
                                                   float* __restrict__ out,
                                                   const float* __restrict__ lng,
                                                   const float* __restrict__ lnb,
                                                   int* __restrict__ lncnt) {
  __shared__ __align__(16) __bf16 Bs[2][3][2][2048];
  __shared__ __align__(16) float qts[1024];
  __shared__ __align__(16) unsigned char rbs[64 * 128];
  __shared__ int lastS;
  const int b = blockIdx.x, it = blockIdx.y, h = blockIdx.z;
  const int t = threadIdx.x, w = t >> 6, l = t & 63;
  const int grp = w >> 2, wq = w & 3;
  const int i0 = it * 64;
  const int dl = l & 15, q = l >> 4, jqf = q * 8;
  const int iA = i0 + wq * 16 + dl;

  const float kvn = kt[(b * Hh + h) * Nn + iA];  // pre-scaled by -log2e
  const float* smrow = sm + b * Nn;

  const int cnt = cntb[b];
  const int stepsTot = (cnt + 63) >> 6;
  const int S = (stepsTot + 1) >> 1;
  const int c0 = grp * S;

  const __bf16* gsrc = gsm + ((size_t)(b * Cc + h * 64 + wq * 16 + (l >> 2))) * Nn
                       + c0 * 64 + (l & 3) * 8;
  __bf16* ring = &Bs[grp][0][0][0];
  const int wdst = wq * 512;
  const int rbbase = (wq * 16 + dl) * 128;

  {
    const float2 qv = *(const float2*)&qt[(b * Hh + h) * Nn + t * 2];
    qts[t * 2 + 0] = qv.x;
    qts[t * 2 + 1] = qv.y;
  }
  {
    const int r = t >> 3, c = (t & 7) * 16;
    const char* src = (const char*)roib + ((size_t)(b * Nn + i0 + r)) * 128 + c;
    *(int4*)&rbs[r * 128 + c] = *(const int4*)src;
  }
  GLL16(gsrc, ring + 0 * 4096 + 0 * 2048 + wdst);
  GLL16(gsrc + 32, ring + 0 * 4096 + 1 * 2048 + wdst);
  GLL16(gsrc + 64, ring + 1 * 4096 + 0 * 2048 + wdst);
  GLL16(gsrc + 96, ring + 1 * 4096 + 1 * 2048 + wdst);
  __syncthreads();

  f32x4 acc[4] = {};
  int cur = 0;

  for (int s = 0; s < S; ++s) {
    const int ck = c0 + s;
    const unsigned int rb0 = rbs[rbbase + ck * 8 + q];
    const unsigned int rb1 = rbs[rbbase + ck * 8 + 4 + q];
    bf16x8 af0, af1;
    {
      fx4 qa = *(const fx4*)&qts[ck * 64 + jqf];
      fx4 qb = *(const fx4*)&qts[ck * 64 + jqf + 4];
#pragma unroll
      for (int e = 0; e < 4; ++e) {
        float sg = __builtin_amdgcn_rcpf(1.f + __builtin_amdgcn_exp2f(qa[e] + kvn));
        af0[e] = (__bf16)(((rb0 >> e) & 1) ? sg : 0.f);
      }
#pragma unroll
      for (int e = 0; e < 4; ++e) {
        float sg = __builtin_amdgcn_rcpf(1.f + __builtin_amdgcn_exp2f(qb[e] + kvn));
        af0[4 + e] = (__bf16)(((rb0 >> (4 + e)) & 1) ? sg : 0.f);
      }
      fx4 qc = *(const fx4*)&qts[ck * 64 + 32 + jqf];
      fx4 qd = *(const fx4*)&qts[ck * 64 + 32 + jqf + 4];
#pragma unroll
      for (int e = 0; e < 4; ++e) {
        float sg = __builtin_amdgcn_rcpf(1.f + __builtin_amdgcn_exp2f(qc[e] + kvn));
        af1[e] = (__bf16)(((rb1 >> e) & 1) ? sg : 0.f);
      }
#pragma unroll
      for (int e = 0; e < 4; ++e) {
        float sg = __builtin_amdgcn_rcpf(1.f + __builtin_amdgcn_exp2f(qd[e] + kvn));
        af1[4 + e] = (__bf16)(((rb1 >> (4 + e)) & 1) ? sg : 0.f);
      }
    }
    asm volatile("s_waitcnt vmcnt(2)\n\ts_barrier" ::: "memory");
    __builtin_amdgcn_sched_barrier(0);
    {
      const int nc = s + 2;
      const int off = (nc < S) ? nc * 64 : 0;
      const int pf = (cur == 0) ? 2 : cur - 1;
      GLL16(gsrc + off, ring + pf * 4096 + 0 * 2048 + wdst);
      GLL16(gsrc + off + 32, ring + pf * 4096 + 1 * 2048 + wdst);
    }
    const __bf16* bp = ring + cur * 4096;
#pragma unroll
    for (int nf = 0; nf < 4; ++nf) {
      bf16x8 bv = *(const bf16x8*)(bp + (nf * 16 + dl) * 32 + jqf);
      acc[nf] = __builtin_amdgcn_mfma_f32_16x16x32_bf16(af0, bv, acc[nf], 0, 0, 0);
    }
#pragma unroll
    for (int nf = 0; nf < 4; ++nf) {
      bf16x8 bv = *(const bf16x8*)(bp + 2048 + (nf * 16 + dl) * 32 + jqf);
      acc[nf] = __builtin_amdgcn_mfma_f32_16x16x32_bf16(af1, bv, acc[nf], 0, 0, 0);
    }
    cur = (cur == 2) ? 0 : cur + 1;
  }

  __syncthreads();  // all GLLs landed; ring free after the combine below
  float* accS = (float*)&Bs[0][0][0][0];
  if (grp == 1) {
#pragma unroll
    for (int nf = 0; nf < 4; ++nf)
      *(f32x4*)&accS[((wq * 64 + l) * 4 + nf) * 4] = acc[nf];
  }
  __syncthreads();
  if (grp == 0) {
#pragma unroll
    for (int nf = 0; nf < 4; ++nf)
      acc[nf] += *(const f32x4*)&accS[((wq * 64 + l) * 4 + nf) * 4];

    const int iw = i0 + wq * 16 + (l >> 4) * 4;
    fx4 sv = *(const fx4*)&smrow[iw];
    float fv[4];
#pragma unroll
    for (int r = 0; r < 4; ++r) fv[r] = (sv[r] == 0.f) ? 0.25f : 0.f;
#pragma unroll
    for (int nf = 0; nf < 4; ++nf) {
      const int ch = h * 64 + nf * 16 + dl;
      fx4 gv = *(const fx4*)&g[((size_t)(b * Cc + ch)) * Nn + iw];
#pragma unroll
      for (int r = 0; r < 4; ++r) {
        const float res = (MODE == 0) ? gv[r] * (1.f + fv[r]) + acc[nf][r]
                                      : acc[nf][r] + fv[r] * gv[r];
        out[((size_t)b * Nn + iw + r) * Cc + ch] = res;  // [B,N,C] both modes
      }
    }
  }

  if (MODE == 1) {
    // ---- last-block LN finisher for (b, it) ----
    __syncthreads();  // drain this block's epilogue stores (vmcnt(0)+barrier)
    if (t == 0) {
      __threadfence();
      const int old = atomicAdd(&lncnt[b * 16 + it], 1);
      if (old == 3) __threadfence();
      lastS = (old == 3) ? 1 : 0;
    }
    __syncthreads();
    if (lastS) {
      float* gt = (float*)&Bs[0][0][0][0];  // [32][258] f32 = 33KB <= 49KB
      const fx4 lngv = *(const fx4*)&lng[l * 4];
      const fx4 lnbv = *(const fx4*)&lnb[l * 4];
#pragma unroll
      for (int chunk = 0; chunk < 2; ++chunk) {
        const int ib = i0 + chunk * 32;
        {
          const int n = t & 31, ch = t >> 5;  // ch in 0..15
#pragma unroll 4
          for (int rr = 0; rr < 16; ++rr) {
            const int c = rr * 16 + ch;
            gt[n * 258 + c] = g[((size_t)(b * Cc + c)) * Nn + ib + n];
          }
        }
        __syncthreads();
#pragma unroll
        for (int r = 0; r < 4; ++r) {
          const int n = r * 8 + w;
          const size_t base = ((size_t)(b * Nn) + ib + n) * Cc + l * 4;
          fx4 v = *(const fx4*)&out[base];
          float s = v[0] + v[1] + v[2] + v[3];
          float sq = v[0] * v[0] + v[1] * v[1] + v[2] * v[2] + v[3] * v[3];
#pragma unroll
          for (int off = 32; off; off >>= 1) {
            s += __shfl_xor(s, off, 64);
            sq += __shfl_xor(sq, off, 64);
          }
          const float m = s * (1.f / 256.f);
          const float var = sq * (1.f / 256.f) - m * m;
          const float rstd = rsqrtf(fmaxf(var, 0.f) + 1e-6f);
          fx4 gv = *(const fx4*)&gt[n * 258 + l * 4];
          fx4 res;
#pragma unroll
          for (int e = 0; e < 4; ++e)
            res[e] = gv[e] + (v[e] - m) * rstd * lngv[e] + lnbv[e];
          *(fx4*)&out[base] = res;
        }
        __syncthreads();  // before next chunk restages gt
      }
    }
  }
}

// ---------------------------------------------------------------------------
extern "C" void kernel_launch(void* const* d_in, const int* in_sizes, int n_in,
                              void* d_out, int out_size, void* d_ws, size_t ws_size,
                              hipStream_t stream) {
  (void)in_sizes; (void)n_in; (void)out_size; (void)ws_size;
  const float* input = (const float*)d_in[0];
  const float* roi   = (const float*)d_in[1];   // masks_roi [B,N,N]
  const float* sm    = (const float*)d_in[2];   // score_mask [B,N]
  const float* spat  = (const float*)d_in[3];
  const float* W1    = (const float*)d_in[4];
  const float* b1    = (const float*)d_in[5];
  const float* W2    = (const float*)d_in[6];
  const float* b2    = (const float*)d_in[7];
  const float* cw1   = (const float*)d_in[8];
  const float* cb1   = (const float*)d_in[9];
  const float* cw2   = (const float*)d_in[10];
  const float* cb2   = (const float*)d_in[11];
  const float* lng   = (const float*)d_in[12];
  const float* lnb   = (const float*)d_in[13];
  // d_in[14] = node_num: unused — scores[b,i,i]=1 is the strict row max, so
  // every column lands in some row's top-k and the `present` mask is all-ones.

  float* outf = (float*)d_out;
  char* ws = (char*)d_ws;
  const size_t PLANE = (size_t)Bb * Cc * Nn;  // 2M elements
  float* gbuf = (float*)ws;                              // conv out f32, 8MB
  __bf16* gsm = (__bf16*)(ws + PLANE * 4);               // 0.25*sm*g bf16, 4MB
  unsigned long long* roib =
      (unsigned long long*)(ws + PLANE * 4 + PLANE * 2); // 1MB (8192 rows x 128B)
  float* qtb = (float*)((char*)roib + (size_t)Bb * Nn * 128);
  float* ktb = qtb + Bb * Hh * Nn;
  int* cntb = (int*)(ktb + Bb * Hh * Nn);                // 8 ints
  int* lncnt = cntb + 8;                                 // 128 ints (LN finisher)
  // d_out doubles as scratch: holds out1 [B,N,C] (apply<0>), then final out.
  float* out1 = outf;

  hipMemsetAsync(lncnt, 0, 128 * sizeof(int), stream);   // capture-safe
  k_roipack2<<<dim3(2048), 256, 0, stream>>>(roi, sm, roib, cntb);
  k_gconvq<<<dim3(8, 32), 256, 0, stream>>>(input, cw1, cb1, sm, spat, W1, b1,
                                            gbuf, gsm, qtb, ktb);
  k_apply7<0><<<dim3(8, 16, 4), 512, 0, stream>>>(gbuf, gsm, qtb, ktb,
                                                  (const unsigned char*)roib, sm,
                                                  cntb, out1, lng, lnb, lncnt);
  k_gconvq<<<dim3(8, 32), 256, 0, stream>>>(out1, cw2, cb2, sm, spat, W2, b2,
                                            gbuf, gsm, qtb, ktb);
  k_apply7<1><<<dim3(8, 16, 4), 512, 0, stream>>>(gbuf, gsm, qtb, ktb,
                                                  (const unsigned char*)roib, sm,
                                                  cntb, outf, lng, lnb, lncnt);
}

// Round 17
// 73.944 us; speedup vs baseline: 1.3246x; 1.3246x over previous
//
#include <hip/hip_runtime.h>

constexpr int Bb = 8;     // batch
constexpr int Nn = 1024;  // nodes
constexpr int Cc = 256;   // channels
constexpr int Hh = 4;     // heads
constexpr int WROW = 2 * Cc + 4;  // 516, same for W1 and W2

typedef float fx4 __attribute__((ext_vector_type(4)));
typedef float f32x4 __attribute__((ext_vector_type(4)));
typedef __bf16 bf16x8 __attribute__((ext_vector_type(8)));

#define GLL16(src, dst)                                                      \
  __builtin_amdgcn_global_load_lds(                                          \
      (const __attribute__((address_space(1))) void*)(src),                  \
      (__attribute__((address_space(3))) void*)(dst), 16, 0, 0)

// ---------------------------------------------------------------------------
// roipack v2 — vectorized roi streaming (r13-proven, session-best config).
// grid 2048, block 256 (4 rows/block).
// ---------------------------------------------------------------------------
__global__ __launch_bounds__(256) void k_roipack2(const float* __restrict__ roi,
                                                  const float* __restrict__ sm,
                                                  unsigned long long* __restrict__ roib,
                                                  int* __restrict__ cntb) {
  __shared__ short jmapS[1024];
  __shared__ unsigned char m4S[4][256];
  __shared__ int cntS;
  const int t = threadIdx.x, w = t >> 6, l = t & 63;
  const int gid = blockIdx.x * 4 + w;
  const int b = gid >> 10;

  if (w == 0) {
    int base = 0;
#pragma unroll
    for (int jc = 0; jc < 16; ++jc) {
      const int j = jc * 64 + l;
      const bool act = sm[b * Nn + j] != 0.f;
      const unsigned long long m = __ballot(act);
      if (act) jmapS[base + __popcll(m & ((1ull << l) - 1))] = (short)j;
      base += __popcll(m);
    }
    if (l == 0) {
      cntS = base;
      if ((blockIdx.x & 255) == 0) cntb[b] = base;
    }
  }
  {
    const fx4* r4 = (const fx4*)(roi + (size_t)gid * Nn);
#pragma unroll
    for (int k = 0; k < 4; ++k) {
      fx4 v = r4[k * 64 + l];
      unsigned nb = (v[0] != 0.f ? 1u : 0u) | (v[1] != 0.f ? 2u : 0u) |
                    (v[2] != 0.f ? 4u : 0u) | (v[3] != 0.f ? 8u : 0u);
      m4S[w][k * 64 + l] = (unsigned char)nb;
    }
  }
  __syncthreads();
  const int cnt = cntS;
  unsigned long long* orow = roib + (size_t)gid * 16;
#pragma unroll 4
  for (int pc = 0; pc < 16; ++pc) {
    const int idx = pc * 64 + l;
    const bool valid = idx < cnt;
    const int j = valid ? (int)jmapS[idx] : 0;
    const bool bit = valid && ((m4S[w][j >> 2] >> (j & 3)) & 1);
    unsigned long long m = __ballot(bit);
    if (l == 0) orow[pc] = m;
  }
}

// ---------------------------------------------------------------------------
// Grouped 1x1 conv (MFMA) + ReLU + fused qt/kt projection (r11/r13-proven).
// STAGE 0: src = input [B,N,C]; STAGE 1: src = out1 [B,C,N].
// xsB chunk XOR-swizzled by (n&7); group g reads chunks g*8..g*8+7.
// qt written at compacted cols pre-scaled by -log2e (+bias), kt full cols.
// grid (8 b, 32 node-tiles), block 256 = 4 waves (wave == group == head).
// ---------------------------------------------------------------------------
template <int STAGE>
__global__ __launch_bounds__(256) void k_gconvq(const float* __restrict__ src,
                                                const float* __restrict__ cw,
                                                const float* __restrict__ cb,
                                                const float* __restrict__ sm,
                                                const float* __restrict__ spat,
                                                const float* __restrict__ W,
                                                const float* __restrict__ bias,
                                                float* __restrict__ out,
                                                __bf16* __restrict__ gsm,
                                                float* __restrict__ qt,
                                                float* __restrict__ kt) {
  __shared__ __align__(16) bf16x8 xsB[32][32];  // [node][c-chunk^swz] 16KB
  __shared__ float cbS[256];
  __shared__ float smS[32];
  __shared__ int pcolS[32];
  __shared__ int actS[32];
  const int b = blockIdx.x, tile = blockIdx.y;
  const int n0 = tile * 32;
  const int t = threadIdx.x, w = t >> 6, l = t & 63;

  // wave 0: compacted-column positions for this tile's 32 nodes
  if (w == 0) {
    const int fullc = n0 >> 6;
    int cbase = 0;
    unsigned long long am = 0;
    for (int jc = 0; jc <= fullc; ++jc) {
      unsigned long long m = __ballot(sm[b * Nn + jc * 64 + l] != 0.f);
      if (jc < fullc) cbase += __popcll(m); else am = m;
    }
    const int lsel = l - (n0 & 63);
    if (lsel >= 0 && lsel < 32) {
      pcolS[lsel] = cbase + __popcll(am & ((1ull << l) - 1));
      actS[lsel] = (int)((am >> l) & 1);
      smS[lsel] = 0.25f * sm[b * Nn + n0 + lsel];
    }
  }
  cbS[t] = cb[t];

  // stage tile into xsB (bf16, chunk-swizzled)
  if (STAGE == 0) {
    const int n = t >> 3, c0 = (t & 7) * 32;
    const float* srow = src + ((size_t)(b * Nn + n0 + n)) * Cc + c0;
#pragma unroll
    for (int k = 0; k < 4; ++k) {
      fx4 v0 = *(const fx4*)&srow[k * 8];
      fx4 v1 = *(const fx4*)&srow[k * 8 + 4];
      bf16x8 bv;
#pragma unroll
      for (int e = 0; e < 4; ++e) { bv[e] = (__bf16)v0[e]; bv[4 + e] = (__bf16)v1[e]; }
      xsB[n][((c0 >> 3) + k) ^ (n & 7)] = bv;
    }
  } else {
#pragma unroll
    for (int rr = 0; rr < 8; ++rr) {
      const int c = rr * 32 + (t >> 3);
      const int nq = (t & 7) * 4;
      fx4 v = *(const fx4*)&src[((size_t)(b * Cc + c)) * Nn + n0 + nq];
#pragma unroll
      for (int j = 0; j < 4; ++j) {
        const int n = nq + j;
        __bf16* row = (__bf16*)&xsB[n][(c >> 3) ^ (n & 7)];
        row[c & 7] = (__bf16)v[j];
      }
    }
  }
  __syncthreads();

  const int g = w, dl = l & 15, q = l >> 4;

  // conv via MFMA: A = cw_g rows (bf16), B = xsB rows (group-g chunks)
  bf16x8 a[4][2];
#pragma unroll
  for (int of = 0; of < 4; ++of)
#pragma unroll
    for (int ks = 0; ks < 2; ++ks) {
      const float* cwp = cw + ((size_t)(g * 64 + of * 16 + dl)) * 64 + ks * 32 + q * 8;
      fx4 c0 = *(const fx4*)cwp;
      fx4 c1 = *(const fx4*)(cwp + 4);
#pragma unroll
      for (int e = 0; e < 4; ++e) { a[of][ks][e] = (__bf16)c0[e]; a[of][ks][4 + e] = (__bf16)c1[e]; }
    }
  f32x4 acc[4][2] = {};
#pragma unroll
  for (int nf = 0; nf < 2; ++nf) {
    const int n = nf * 16 + dl;
#pragma unroll
    for (int ks = 0; ks < 2; ++ks) {
      bf16x8 bv = xsB[n][(g * 8 + ks * 4 + q) ^ (n & 7)];  // group-g chunks
#pragma unroll
      for (int of = 0; of < 4; ++of)
        acc[of][nf] = __builtin_amdgcn_mfma_f32_16x16x32_bf16(a[of][ks], bv, acc[of][nf], 0, 0, 0);
    }
  }
  // epilogue: D row = 4q+r -> co, col = dl -> node
#pragma unroll
  for (int of = 0; of < 4; ++of)
#pragma unroll
    for (int nf = 0; nf < 2; ++nf) {
      const int n = nf * 16 + dl;
      const float smv = smS[n];
      const int act = actS[n];
      const int pc = pcolS[n];
#pragma unroll
      for (int r = 0; r < 4; ++r) {
        const int co = g * 64 + of * 16 + 4 * q + r;
        const float val = fmaxf(acc[of][nf][r] + cbS[co], 0.f);
        const size_t orow = ((size_t)(b * Cc + co)) * Nn;
        out[orow + n0 + n] = val;
        if (act) gsm[orow + pc] = (__bf16)(smv * val);
      }
    }

  // qt/kt projection: 2 lanes per node, split-C + shfl combine
  {
    const int nl = l & 31, half = l >> 5;
    const float* wq = W + g * WROW;
    const float* wk = wq + Cc;
    float qa = 0.f, ka = 0.f;
#pragma unroll 8
    for (int c2 = 0; c2 < 64; ++c2) {
      const int c = half * 128 + c2 * 2;
      const __bf16* p = (const __bf16*)&xsB[nl][(c >> 3) ^ (nl & 7)] + (c & 7);
      const float x0 = (float)p[0], x1 = (float)p[1];
      qa = fmaf(x0, wq[c], fmaf(x1, wq[c + 1], qa));
      ka = fmaf(x0, wk[c], fmaf(x1, wk[c + 1], ka));
    }
    qa += __shfl_xor(qa, 32, 64);
    ka += __shfl_xor(ka, 32, 64);
    if (l < 32) {
      const int n = n0 + nl;
      const float s0 = spat[(b * Nn + n) * 2 + 0];
      const float s1 = spat[(b * Nn + n) * 2 + 1];
      const float* wsp = W + g * WROW + 2 * Cc;
      const float qf = qa + s0 * wsp[0] + s1 * wsp[1] + bias[g];
      const float kf = ka + s0 * wsp[2] + s1 * wsp[3];
      kt[(b * Hh + g) * Nn + n] = kf * -1.44269504f;
      if (actS[nl]) qt[(b * Hh + g) * Nn + pcolS[nl]] = qf * -1.44269504f;
    }
  }
}

// ---------------------------------------------------------------------------
// MFMA fused attention apply, v7 (r9-proven; cnt from cntb).
// Per block (b, it, h): C[i,d] = 0.25*sum_j sig(qt[j]+kt[i])*mask[i,j]*G[d,j]
// K-compacted; per-group private 3-buffer LDS ring; 2 GLLs/wave/step with
// uniform dummy-GLL tail so vmcnt(2) == "buf s landed" at every step.
// grid dim3(8 b, 16 it, 4 h): linear%8 == b -> each XCD serves one batch.
// ---------------------------------------------------------------------------
template <int MODE>
__global__ __launch_bounds__(512, 4) void k_apply7(const float* __restrict__ g,
                                                   const __bf16* __restrict__ gsm,
                                                   const float* __restrict__ qt,
                                                   const float* __restrict__ kt,
                                                   const unsigned char* __restrict__ roib,
                                                   const float* __restrict__ sm,
                                                   const int* __restrict__ cntb,
                                                   float* __restrict__ out) {
  __shared__ __align__(16) __bf16 Bs[2][3][2][2048];
  __shared__ __align__(16) float qts[1024];
  __shared__ __align__(16) unsigned char rbs[64 * 128];
  const int b = blockIdx.x, it = blockIdx.y, h = blockIdx.z;
  const int t = threadIdx.x, w = t >> 6, l = t & 63;
  const int grp = w >> 2, wq = w & 3;
  const int i0 = it * 64;
  const int dl = l & 15, q = l >> 4, jqf = q * 8;
  const int iA = i0 + wq * 16 + dl;

  const float kvn = kt[(b * Hh + h) * Nn + iA];  // pre-scaled by -log2e
  const float* smrow = sm + b * Nn;

  const int cnt = cntb[b];
  const int stepsTot = (cnt + 63) >> 6;
  const int S = (stepsTot + 1) >> 1;
  const int c0 = grp * S;

  const __bf16* gsrc = gsm + ((size_t)(b * Cc + h * 64 + wq * 16 + (l >> 2))) * Nn
                       + c0 * 64 + (l & 3) * 8;
  __bf16* ring = &Bs[grp][0][0][0];
  const int wdst = wq * 512;
  const int rbbase = (wq * 16 + dl) * 128;

  {
    const float2 qv = *(const float2*)&qt[(b * Hh + h) * Nn + t * 2];
    qts[t * 2 + 0] = qv.x;
    qts[t * 2 + 1] = qv.y;
  }
  {
    const int r = t >> 3, c = (t & 7) * 16;
    const char* src = (const char*)roib + ((size_t)(b * Nn + i0 + r)) * 128 + c;
    *(int4*)&rbs[r * 128 + c] = *(const int4*)src;
  }
  GLL16(gsrc, ring + 0 * 4096 + 0 * 2048 + wdst);
  GLL16(gsrc + 32, ring + 0 * 4096 + 1 * 2048 + wdst);
  GLL16(gsrc + 64, ring + 1 * 4096 + 0 * 2048 + wdst);
  GLL16(gsrc + 96, ring + 1 * 4096 + 1 * 2048 + wdst);
  __syncthreads();

  f32x4 acc[4] = {};
  int cur = 0;

  for (int s = 0; s < S; ++s) {
    const int ck = c0 + s;
    const unsigned int rb0 = rbs[rbbase + ck * 8 + q];
    const unsigned int rb1 = rbs[rbbase + ck * 8 + 4 + q];
    bf16x8 af0, af1;
    {
      fx4 qa = *(const fx4*)&qts[ck * 64 + jqf];
      fx4 qb = *(const fx4*)&qts[ck * 64 + jqf + 4];
#pragma unroll
      for (int e = 0; e < 4; ++e) {
        float sg = __builtin_amdgcn_rcpf(1.f + __builtin_amdgcn_exp2f(qa[e] + kvn));
        af0[e] = (__bf16)(((rb0 >> e) & 1) ? sg : 0.f);
      }
#pragma unroll
      for (int e = 0; e < 4; ++e) {
        float sg = __builtin_amdgcn_rcpf(1.f + __builtin_amdgcn_exp2f(qb[e] + kvn));
        af0[4 + e] = (__bf16)(((rb0 >> (4 + e)) & 1) ? sg : 0.f);
      }
      fx4 qc = *(const fx4*)&qts[ck * 64 + 32 + jqf];
      fx4 qd = *(const fx4*)&qts[ck * 64 + 32 + jqf + 4];
#pragma unroll
      for (int e = 0; e < 4; ++e) {
        float sg = __builtin_amdgcn_rcpf(1.f + __builtin_amdgcn_exp2f(qc[e] + kvn));
        af1[e] = (__bf16)(((rb1 >> e) & 1) ? sg : 0.f);
      }
#pragma unroll
      for (int e = 0; e < 4; ++e) {
        float sg = __builtin_amdgcn_rcpf(1.f + __builtin_amdgcn_exp2f(qd[e] + kvn));
        af1[4 + e] = (__bf16)(((rb1 >> (4 + e)) & 1) ? sg : 0.f);
      }
    }
    asm volatile("s_waitcnt vmcnt(2)\n\ts_barrier" ::: "memory");
    __builtin_amdgcn_sched_barrier(0);
    {
      const int nc = s + 2;
      const int off = (nc < S) ? nc * 64 : 0;
      const int pf = (cur == 0) ? 2 : cur - 1;
      GLL16(gsrc + off, ring + pf * 4096 + 0 * 2048 + wdst);
      GLL16(gsrc + off + 32, ring + pf * 4096 + 1 * 2048 + wdst);
    }
    const __bf16* bp = ring + cur * 4096;
#pragma unroll
    for (int nf = 0; nf < 4; ++nf) {
      bf16x8 bv = *(const bf16x8*)(bp + (nf * 16 + dl) * 32 + jqf);
      acc[nf] = __builtin_amdgcn_mfma_f32_16x16x32_bf16(af0, bv, acc[nf], 0, 0, 0);
    }
#pragma unroll
    for (int nf = 0; nf < 4; ++nf) {
      bf16x8 bv = *(const bf16x8*)(bp + 2048 + (nf * 16 + dl) * 32 + jqf);
      acc[nf] = __builtin_amdgcn_mfma_f32_16x16x32_bf16(af1, bv, acc[nf], 0, 0, 0);
    }
    cur = (cur == 2) ? 0 : cur + 1;
  }

  __syncthreads();
  float* accS = (float*)&Bs[0][0][0][0];
  if (grp == 1) {
#pragma unroll
    for (int nf = 0; nf < 4; ++nf)
      *(f32x4*)&accS[((wq * 64 + l) * 4 + nf) * 4] = acc[nf];
  }
  __syncthreads();
  if (grp == 0) {
#pragma unroll
    for (int nf = 0; nf < 4; ++nf)
      acc[nf] += *(const f32x4*)&accS[((wq * 64 + l) * 4 + nf) * 4];

    const int iw = i0 + wq * 16 + (l >> 4) * 4;
    fx4 sv = *(const fx4*)&smrow[iw];
    float fv[4];
#pragma unroll
    for (int r = 0; r < 4; ++r) fv[r] = (sv[r] == 0.f) ? 0.25f : 0.f;
    if (MODE == 0) {
#pragma unroll
      for (int nf = 0; nf < 4; ++nf) {
        const int ch = h * 64 + nf * 16 + dl;
        const size_t base = ((size_t)(b * Cc + ch)) * Nn + iw;
        fx4 gv = *(const fx4*)&g[base];
        fx4 res;
#pragma unroll
        for (int r = 0; r < 4; ++r) res[r] = gv[r] * (1.f + fv[r]) + acc[nf][r];
        *(fx4*)&out[base] = res;
      }
    } else {
#pragma unroll
      for (int nf = 0; nf < 4; ++nf) {
        const int ch = h * 64 + nf * 16 + dl;
        fx4 gv = *(const fx4*)&g[((size_t)(b * Cc + ch)) * Nn + iw];
#pragma unroll
        for (int r = 0; r < 4; ++r)
          out[((size_t)b * Nn + iw + r) * Cc + ch] = acc[nf][r] + fv[r] * gv[r];
      }
    }
  }
}

// ---------------------------------------------------------------------------
// Fused LayerNorm stats + final residual add, one pass (r13-proven).
// ---------------------------------------------------------------------------
__global__ __launch_bounds__(256) void k_lnfinal(float* __restrict__ io,
                                                 const float* __restrict__ g2,
                                                 const float* __restrict__ lng,
                                                 const float* __restrict__ lnb) {
  __shared__ float gt[32][258];
  const int b = blockIdx.x, i0 = blockIdx.y * 32;
  const int t = threadIdx.x, w = t >> 6, l = t & 63;
  {
    const int n = t & 31, ch = t >> 5;
#pragma unroll 8
    for (int rr = 0; rr < 32; ++rr) {
      int c = rr * 8 + ch;
      gt[n][c] = g2[((size_t)(b * Cc + c)) * Nn + i0 + n];
    }
  }
  __syncthreads();
  const fx4 lngv = *(const fx4*)&lng[l * 4];
  const fx4 lnbv = *(const fx4*)&lnb[l * 4];
#pragma unroll
  for (int r = 0; r < 8; ++r) {
    const int n = r * 4 + w;
    const size_t base = ((size_t)(b * Nn) + i0 + n) * Cc + l * 4;
    fx4 v = *(const fx4*)&io[base];
    float s = v[0] + v[1] + v[2] + v[3];
    float sq = v[0] * v[0] + v[1] * v[1] + v[2] * v[2] + v[3] * v[3];
#pragma unroll
    for (int off = 32; off; off >>= 1) {
      s += __shfl_xor(s, off, 64);
      sq += __shfl_xor(sq, off, 64);
    }
    const float m = s * (1.f / 256.f);
    const float var = sq * (1.f / 256.f) - m * m;
    const float rstd = rsqrtf(fmaxf(var, 0.f) + 1e-6f);
    fx4 gv = *(const fx4*)&gt[n][l * 4];
    fx4 res;
#pragma unroll
    for (int e = 0; e < 4; ++e)
      res[e] = gv[e] + (v[e] - m) * rstd * lngv[e] + lnbv[e];
    *(fx4*)&io[base] = res;
  }
}

// ---------------------------------------------------------------------------
extern "C" void kernel_launch(void* const* d_in, const int* in_sizes, int n_in,
                              void* d_out, int out_size, void* d_ws, size_t ws_size,
                              hipStream_t stream) {
  (void)in_sizes; (void)n_in; (void)out_size; (void)ws_size;
  const float* input = (const float*)d_in[0];
  const float* roi   = (const float*)d_in[1];   // masks_roi [B,N,N]
  const float* sm    = (const float*)d_in[2];   // score_mask [B,N]
  const float* spat  = (const float*)d_in[3];
  const float* W1    = (const float*)d_in[4];
  const float* b1    = (const float*)d_in[5];
  const float* W2    = (const float*)d_in[6];
  const float* b2    = (const float*)d_in[7];
  const float* cw1   = (const float*)d_in[8];
  const float* cb1   = (const float*)d_in[9];
  const float* cw2   = (const float*)d_in[10];
  const float* cb2   = (const float*)d_in[11];
  const float* lng   = (const float*)d_in[12];
  const float* lnb   = (const float*)d_in[13];
  // d_in[14] = node_num: unused — scores[b,i,i]=1 is the strict row max, so
  // every column lands in some row's top-k and the `present` mask is all-ones.

  float* outf = (float*)d_out;
  char* ws = (char*)d_ws;
  const size_t PLANE = (size_t)Bb * Cc * Nn;  // 2M elements
  float* gbuf = (float*)ws;                              // conv out f32, 8MB
  __bf16* gsm = (__bf16*)(ws + PLANE * 4);               // 0.25*sm*g bf16, 4MB
  unsigned long long* roib =
      (unsigned long long*)(ws + PLANE * 4 + PLANE * 2); // 1MB (8192 rows x 128B)
  float* qtb = (float*)((char*)roib + (size_t)Bb * Nn * 128);
  float* ktb = qtb + Bb * Hh * Nn;
  int* cntb = (int*)(ktb + Bb * Hh * Nn);                // 8 ints
  // d_out doubles as scratch: holds out1 [B,C,N] (apply1), then final out.
  float* out1 = outf;

  k_roipack2<<<dim3(2048), 256, 0, stream>>>(roi, sm, roib, cntb);
  k_gconvq<0><<<dim3(8, 32), 256, 0, stream>>>(input, cw1, cb1, sm, spat, W1, b1,
                                               gbuf, gsm, qtb, ktb);
  k_apply7<0><<<dim3(8, 16, 4), 512, 0, stream>>>(gbuf, gsm, qtb, ktb,
                                                  (const unsigned char*)roib, sm,
                                                  cntb, out1);
  k_gconvq<1><<<dim3(8, 32), 256, 0, stream>>>(out1, cw2, cb2, sm, spat, W2, b2,
                                               gbuf, gsm, qtb, ktb);
  k_apply7<1><<<dim3(8, 16, 4), 512, 0, stream>>>(gbuf, gsm, qtb, ktb,
                                                  (const unsigned char*)roib, sm,
                                                  cntb, outf);
  k_lnfinal<<<dim3(8, 32), 256, 0, stream>>>(outf, gbuf, lng, lnb);
}

// Round 18
// 73.497 us; speedup vs baseline: 1.3326x; 1.0061x over previous
//
#include <hip/hip_runtime.h>

constexpr int Bb = 8;     // batch
constexpr int Nn = 1024;  // nodes
constexpr int Cc = 256;   // channels
constexpr int Hh = 4;     // heads
constexpr int WROW = 2 * Cc + 4;  // 516, same for W1 and W2

typedef float fx4 __attribute__((ext_vector_type(4)));
typedef float f32x4 __attribute__((ext_vector_type(4)));
typedef __bf16 bf16x8 __attribute__((ext_vector_type(8)));

#define GLL16(src, dst)                                                      \
  __builtin_amdgcn_global_load_lds(                                          \
      (const __attribute__((address_space(1))) void*)(src),                  \
      (__attribute__((address_space(3))) void*)(dst), 16, 0, 0)

// ---------------------------------------------------------------------------
// Merged front dispatch: blocks [0,256) = gconv STAGE-0 (b = bid&7 keeps
// batch->XCD affinity), blocks [256,2304) = roipack v2 (fx4-nibble variant,
// 16 ballots/row — NOT r12's 32-ballot chain). Both halves byte-identical to
// the r17-proven kernels; no shared state.
// ---------------------------------------------------------------------------
__global__ __launch_bounds__(256) void k_rpgc0(const float* __restrict__ src,
                                               const float* __restrict__ cw,
                                               const float* __restrict__ cb,
                                               const float* __restrict__ sm,
                                               const float* __restrict__ spat,
                                               const float* __restrict__ W,
                                               const float* __restrict__ bias,
                                               float* __restrict__ out,
                                               __bf16* __restrict__ gsm,
                                               float* __restrict__ qt,
                                               float* __restrict__ kt,
                                               const float* __restrict__ roi,
                                               unsigned long long* __restrict__ roib,
                                               int* __restrict__ cntb) {
  // gconv LDS
  __shared__ __align__(16) bf16x8 xsB[32][32];  // 16KB
  __shared__ float cbS[256];
  __shared__ float smS[32];
  __shared__ int pcolS[32];
  __shared__ int actS[32];
  // roipack LDS
  __shared__ short jmapS[1024];                 // 2KB
  __shared__ unsigned char m4S[4][256];         // 1KB
  __shared__ int cntS;

  const int t = threadIdx.x, w = t >> 6, l = t & 63;

  if (blockIdx.x >= 256) {
    // =================== roipack v2 (r13/r17-proven) ===================
    const int vb2 = blockIdx.x - 256;  // [0,2048)
    const int gid = vb2 * 4 + w;       // row over B*N (4 rows, same batch)
    const int b = gid >> 10;

    if (w == 0) {
      int base = 0;
#pragma unroll
      for (int jc = 0; jc < 16; ++jc) {
        const int j = jc * 64 + l;
        const bool act = sm[b * Nn + j] != 0.f;
        const unsigned long long m = __ballot(act);
        if (act) jmapS[base + __popcll(m & ((1ull << l) - 1))] = (short)j;
        base += __popcll(m);
      }
      if (l == 0) {
        cntS = base;
        if ((vb2 & 255) == 0) cntb[b] = base;
      }
    }
    {
      const fx4* r4 = (const fx4*)(roi + (size_t)gid * Nn);
#pragma unroll
      for (int k = 0; k < 4; ++k) {
        fx4 v = r4[k * 64 + l];
        unsigned nb = (v[0] != 0.f ? 1u : 0u) | (v[1] != 0.f ? 2u : 0u) |
                      (v[2] != 0.f ? 4u : 0u) | (v[3] != 0.f ? 8u : 0u);
        m4S[w][k * 64 + l] = (unsigned char)nb;
      }
    }
    __syncthreads();
    const int cnt = cntS;
    unsigned long long* orow = roib + (size_t)gid * 16;
#pragma unroll 4
    for (int pc = 0; pc < 16; ++pc) {
      const int idx = pc * 64 + l;
      const bool valid = idx < cnt;
      const int j = valid ? (int)jmapS[idx] : 0;
      const bool bit = valid && ((m4S[w][j >> 2] >> (j & 3)) & 1);
      unsigned long long m = __ballot(bit);
      if (l == 0) orow[pc] = m;
    }
    return;
  }

  // =================== gconv STAGE-0 (r17-proven body) ===================
  const int b = blockIdx.x & 7, tile = blockIdx.x >> 3;
  const int n0 = tile * 32;

  if (w == 0) {
    const int fullc = n0 >> 6;
    int cbase = 0;
    unsigned long long am = 0;
    for (int jc = 0; jc <= fullc; ++jc) {
      unsigned long long m = __ballot(sm[b * Nn + jc * 64 + l] != 0.f);
      if (jc < fullc) cbase += __popcll(m); else am = m;
    }
    const int lsel = l - (n0 & 63);
    if (lsel >= 0 && lsel < 32) {
      pcolS[lsel] = cbase + __popcll(am & ((1ull << l) - 1));
      actS[lsel] = (int)((am >> l) & 1);
      smS[lsel] = 0.25f * sm[b * Nn + n0 + lsel];
    }
  }
  cbS[t] = cb[t];

  {
    const int n = t >> 3, c0 = (t & 7) * 32;
    const float* srow = src + ((size_t)(b * Nn + n0 + n)) * Cc + c0;
#pragma unroll
    for (int k = 0; k < 4; ++k) {
      fx4 v0 = *(const fx4*)&srow[k * 8];
      fx4 v1 = *(const fx4*)&srow[k * 8 + 4];
      bf16x8 bv;
#pragma unroll
      for (int e = 0; e < 4; ++e) { bv[e] = (__bf16)v0[e]; bv[4 + e] = (__bf16)v1[e]; }
      xsB[n][((c0 >> 3) + k) ^ (n & 7)] = bv;
    }
  }

  const int g = w, dl = l & 15, q = l >> 4;

  bf16x8 a[4][2];
#pragma unroll
  for (int of = 0; of < 4; ++of)
#pragma unroll
    for (int ks = 0; ks < 2; ++ks) {
      const float* cwp = cw + ((size_t)(g * 64 + of * 16 + dl)) * 64 + ks * 32 + q * 8;
      fx4 c0 = *(const fx4*)cwp;
      fx4 c1 = *(const fx4*)(cwp + 4);
#pragma unroll
      for (int e = 0; e < 4; ++e) { a[of][ks][e] = (__bf16)c0[e]; a[of][ks][4 + e] = (__bf16)c1[e]; }
    }
  __syncthreads();

  f32x4 acc[4][2] = {};
#pragma unroll
  for (int nf = 0; nf < 2; ++nf) {
    const int n = nf * 16 + dl;
#pragma unroll
    for (int ks = 0; ks < 2; ++ks) {
      bf16x8 bv = xsB[n][(g * 8 + ks * 4 + q) ^ (n & 7)];
#pragma unroll
      for (int of = 0; of < 4; ++of)
        acc[of][nf] = __builtin_amdgcn_mfma_f32_16x16x32_bf16(a[of][ks], bv, acc[of][nf], 0, 0, 0);
    }
  }
#pragma unroll
  for (int of = 0; of < 4; ++of)
#pragma unroll
    for (int nf = 0; nf < 2; ++nf) {
      const int n = nf * 16 + dl;
      const float smv = smS[n];
      const int act = actS[n];
      const int pc = pcolS[n];
#pragma unroll
      for (int r = 0; r < 4; ++r) {
        const int co = g * 64 + of * 16 + 4 * q + r;
        const float val = fmaxf(acc[of][nf][r] + cbS[co], 0.f);
        const size_t orow = ((size_t)(b * Cc + co)) * Nn;
        out[orow + n0 + n] = val;
        if (act) gsm[orow + pc] = (__bf16)(smv * val);
      }
    }

  {
    const int nl = l & 31, half = l >> 5;
    const float* wq = W + g * WROW;
    const float* wk = wq + Cc;
    float qa = 0.f, ka = 0.f;
#pragma unroll 8
    for (int c2 = 0; c2 < 64; ++c2) {
      const int c = half * 128 + c2 * 2;
      const __bf16* p = (const __bf16*)&xsB[nl][(c >> 3) ^ (nl & 7)] + (c & 7);
      const float x0 = (float)p[0], x1 = (float)p[1];
      qa = fmaf(x0, wq[c], fmaf(x1, wq[c + 1], qa));
      ka = fmaf(x0, wk[c], fmaf(x1, wk[c + 1], ka));
    }
    qa += __shfl_xor(qa, 32, 64);
    ka += __shfl_xor(ka, 32, 64);
    if (l < 32) {
      const int n = n0 + nl;
      const float s0 = spat[(b * Nn + n) * 2 + 0];
      const float s1 = spat[(b * Nn + n) * 2 + 1];
      const float* wsp = W + g * WROW + 2 * Cc;
      const float qf = qa + s0 * wsp[0] + s1 * wsp[1] + bias[g];
      const float kf = ka + s0 * wsp[2] + s1 * wsp[3];
      kt[(b * Hh + g) * Nn + n] = kf * -1.44269504f;
      if (actS[nl]) qt[(b * Hh + g) * Nn + pcolS[nl]] = qf * -1.44269504f;
    }
  }
}

// ---------------------------------------------------------------------------
// Grouped 1x1 conv (MFMA) + ReLU + fused qt/kt projection (r17-proven).
// STAGE 1: src = out1 [B,C,N]. grid (8 b, 32 node-tiles), block 256.
// ---------------------------------------------------------------------------
__global__ __launch_bounds__(256) void k_gconvq1(const float* __restrict__ src,
                                                 const float* __restrict__ cw,
                                                 const float* __restrict__ cb,
                                                 const float* __restrict__ sm,
                                                 const float* __restrict__ spat,
                                                 const float* __restrict__ W,
                                                 const float* __restrict__ bias,
                                                 float* __restrict__ out,
                                                 __bf16* __restrict__ gsm,
                                                 float* __restrict__ qt,
                                                 float* __restrict__ kt) {
  __shared__ __align__(16) bf16x8 xsB[32][32];
  __shared__ float cbS[256];
  __shared__ float smS[32];
  __shared__ int pcolS[32];
  __shared__ int actS[32];
  const int b = blockIdx.x, tile = blockIdx.y;
  const int n0 = tile * 32;
  const int t = threadIdx.x, w = t >> 6, l = t & 63;

  if (w == 0) {
    const int fullc = n0 >> 6;
    int cbase = 0;
    unsigned long long am = 0;
    for (int jc = 0; jc <= fullc; ++jc) {
      unsigned long long m = __ballot(sm[b * Nn + jc * 64 + l] != 0.f);
      if (jc < fullc) cbase += __popcll(m); else am = m;
    }
    const int lsel = l - (n0 & 63);
    if (lsel >= 0 && lsel < 32) {
      pcolS[lsel] = cbase + __popcll(am & ((1ull << l) - 1));
      actS[lsel] = (int)((am >> l) & 1);
      smS[lsel] = 0.25f * sm[b * Nn + n0 + lsel];
    }
  }
  cbS[t] = cb[t];

#pragma unroll
  for (int rr = 0; rr < 8; ++rr) {
    const int c = rr * 32 + (t >> 3);
    const int nq = (t & 7) * 4;
    fx4 v = *(const fx4*)&src[((size_t)(b * Cc + c)) * Nn + n0 + nq];
#pragma unroll
    for (int j = 0; j < 4; ++j) {
      const int n = nq + j;
      __bf16* row = (__bf16*)&xsB[n][(c >> 3) ^ (n & 7)];
      row[c & 7] = (__bf16)v[j];
    }
  }
  __syncthreads();

  const int g = w, dl = l & 15, q = l >> 4;

  bf16x8 a[4][2];
#pragma unroll
  for (int of = 0; of < 4; ++of)
#pragma unroll
    for (int ks = 0; ks < 2; ++ks) {
      const float* cwp = cw + ((size_t)(g * 64 + of * 16 + dl)) * 64 + ks * 32 + q * 8;
      fx4 c0 = *(const fx4*)cwp;
      fx4 c1 = *(const fx4*)(cwp + 4);
#pragma unroll
      for (int e = 0; e < 4; ++e) { a[of][ks][e] = (__bf16)c0[e]; a[of][ks][4 + e] = (__bf16)c1[e]; }
    }
  f32x4 acc[4][2] = {};
#pragma unroll
  for (int nf = 0; nf < 2; ++nf) {
    const int n = nf * 16 + dl;
#pragma unroll
    for (int ks = 0; ks < 2; ++ks) {
      bf16x8 bv = xsB[n][(g * 8 + ks * 4 + q) ^ (n & 7)];
#pragma unroll
      for (int of = 0; of < 4; ++of)
        acc[of][nf] = __builtin_amdgcn_mfma_f32_16x16x32_bf16(a[of][ks], bv, acc[of][nf], 0, 0, 0);
    }
  }
#pragma unroll
  for (int of = 0; of < 4; ++of)
#pragma unroll
    for (int nf = 0; nf < 2; ++nf) {
      const int n = nf * 16 + dl;
      const float smv = smS[n];
      const int act = actS[n];
      const int pc = pcolS[n];
#pragma unroll
      for (int r = 0; r < 4; ++r) {
        const int co = g * 64 + of * 16 + 4 * q + r;
        const float val = fmaxf(acc[of][nf][r] + cbS[co], 0.f);
        const size_t orow = ((size_t)(b * Cc + co)) * Nn;
        out[orow + n0 + n] = val;
        if (act) gsm[orow + pc] = (__bf16)(smv * val);
      }
    }

  {
    const int nl = l & 31, half = l >> 5;
    const float* wq = W + g * WROW;
    const float* wk = wq + Cc;
    float qa = 0.f, ka = 0.f;
#pragma unroll 8
    for (int c2 = 0; c2 < 64; ++c2) {
      const int c = half * 128 + c2 * 2;
      const __bf16* p = (const __bf16*)&xsB[nl][(c >> 3) ^ (nl & 7)] + (c & 7);
      const float x0 = (float)p[0], x1 = (float)p[1];
      qa = fmaf(x0, wq[c], fmaf(x1, wq[c + 1], qa));
      ka = fmaf(x0, wk[c], fmaf(x1, wk[c + 1], ka));
    }
    qa += __shfl_xor(qa, 32, 64);
    ka += __shfl_xor(ka, 32, 64);
    if (l < 32) {
      const int n = n0 + nl;
      const float s0 = spat[(b * Nn + n) * 2 + 0];
      const float s1 = spat[(b * Nn + n) * 2 + 1];
      const float* wsp = W + g * WROW + 2 * Cc;
      const float qf = qa + s0 * wsp[0] + s1 * wsp[1] + bias[g];
      const float kf = ka + s0 * wsp[2] + s1 * wsp[3];
      kt[(b * Hh + g) * Nn + n] = kf * -1.44269504f;
      if (actS[nl]) qt[(b * Hh + g) * Nn + pcolS[nl]] = qf * -1.44269504f;
    }
  }
}

// ---------------------------------------------------------------------------
// MFMA fused attention apply, v7 (r9/r17-proven; cnt from cntb).
// grid dim3(8 b, 16 it, 4 h): linear%8 == b -> each XCD serves one batch.
// ---------------------------------------------------------------------------
template <int MODE>
__global__ __launch_bounds__(512, 4) void k_apply7(const float* __restrict__ g,
                                                   const __bf16* __restrict__ gsm,
                                                   const float* __restrict__ qt,
                                                   const float* __restrict__ kt,
                                                   const unsigned char* __restrict__ roib,
                                                   const float* __restrict__ sm,
                                                   const int* __restrict__ cntb,
                                                   float* __restrict__ out) {
  __shared__ __align__(16) __bf16 Bs[2][3][2][2048];
  __shared__ __align__(16) float qts[1024];
  __shared__ __align__(16) unsigned char rbs[64 * 128];
  const int b = blockIdx.x, it = blockIdx.y, h = blockIdx.z;
  const int t = threadIdx.x, w = t >> 6, l = t & 63;
  const int grp = w >> 2, wq = w & 3;
  const int i0 = it * 64;
  const int dl = l & 15, q = l >> 4, jqf = q * 8;
  const int iA = i0 + wq * 16 + dl;

  const float kvn = kt[(b * Hh + h) * Nn + iA];  // pre-scaled by -log2e
  const float* smrow = sm + b * Nn;

  const int cnt = cntb[b];
  const int stepsTot = (cnt + 63) >> 6;
  const int S = (stepsTot + 1) >> 1;
  const int c0 = grp * S;

  const __bf16* gsrc = gsm + ((size_t)(b * Cc + h * 64 + wq * 16 + (l >> 2))) * Nn
                       + c0 * 64 + (l & 3) * 8;
  __bf16* ring = &Bs[grp][0][0][0];
  const int wdst = wq * 512;
  const int rbbase = (wq * 16 + dl) * 128;

  {
    const float2 qv = *(const float2*)&qt[(b * Hh + h) * Nn + t * 2];
    qts[t * 2 + 0] = qv.x;
    qts[t * 2 + 1] = qv.y;
  }
  {
    const int r = t >> 3, c = (t & 7) * 16;
    const char* src = (const char*)roib + ((size_t)(b * Nn + i0 + r)) * 128 + c;
    *(int4*)&rbs[r * 128 + c] = *(const int4*)src;
  }
  GLL16(gsrc, ring + 0 * 4096 + 0 * 2048 + wdst);
  GLL16(gsrc + 32, ring + 0 * 4096 + 1 * 2048 + wdst);
  GLL16(gsrc + 64, ring + 1 * 4096 + 0 * 2048 + wdst);
  GLL16(gsrc + 96, ring + 1 * 4096 + 1 * 2048 + wdst);
  __syncthreads();

  f32x4 acc[4] = {};
  int cur = 0;

  for (int s = 0; s < S; ++s) {
    const int ck = c0 + s;
    const unsigned int rb0 = rbs[rbbase + ck * 8 + q];
    const unsigned int rb1 = rbs[rbbase + ck * 8 + 4 + q];
    bf16x8 af0, af1;
    {
      fx4 qa = *(const fx4*)&qts[ck * 64 + jqf];
      fx4 qb = *(const fx4*)&qts[ck * 64 + jqf + 4];
#pragma unroll
      for (int e = 0; e < 4; ++e) {
        float sg = __builtin_amdgcn_rcpf(1.f + __builtin_amdgcn_exp2f(qa[e] + kvn));
        af0[e] = (__bf16)(((rb0 >> e) & 1) ? sg : 0.f);
      }
#pragma unroll
      for (int e = 0; e < 4; ++e) {
        float sg = __builtin_amdgcn_rcpf(1.f + __builtin_amdgcn_exp2f(qb[e] + kvn));
        af0[4 + e] = (__bf16)(((rb0 >> (4 + e)) & 1) ? sg : 0.f);
      }
      fx4 qc = *(const fx4*)&qts[ck * 64 + 32 + jqf];
      fx4 qd = *(const fx4*)&qts[ck * 64 + 32 + jqf + 4];
#pragma unroll
      for (int e = 0; e < 4; ++e) {
        float sg = __builtin_amdgcn_rcpf(1.f + __builtin_amdgcn_exp2f(qc[e] + kvn));
        af1[e] = (__bf16)(((rb1 >> e) & 1) ? sg : 0.f);
      }
#pragma unroll
      for (int e = 0; e < 4; ++e) {
        float sg = __builtin_amdgcn_rcpf(1.f + __builtin_amdgcn_exp2f(qd[e] + kvn));
        af1[4 + e] = (__bf16)(((rb1 >> (4 + e)) & 1) ? sg : 0.f);
      }
    }
    asm volatile("s_waitcnt vmcnt(2)\n\ts_barrier" ::: "memory");
    __builtin_amdgcn_sched_barrier(0);
    {
      const int nc = s + 2;
      const int off = (nc < S) ? nc * 64 : 0;
      const int pf = (cur == 0) ? 2 : cur - 1;
      GLL16(gsrc + off, ring + pf * 4096 + 0 * 2048 + wdst);
      GLL16(gsrc + off + 32, ring + pf * 4096 + 1 * 2048 + wdst);
    }
    const __bf16* bp = ring + cur * 4096;
#pragma unroll
    for (int nf = 0; nf < 4; ++nf) {
      bf16x8 bv = *(const bf16x8*)(bp + (nf * 16 + dl) * 32 + jqf);
      acc[nf] = __builtin_amdgcn_mfma_f32_16x16x32_bf16(af0, bv, acc[nf], 0, 0, 0);
    }
#pragma unroll
    for (int nf = 0; nf < 4; ++nf) {
      bf16x8 bv = *(const bf16x8*)(bp + 2048 + (nf * 16 + dl) * 32 + jqf);
      acc[nf] = __builtin_amdgcn_mfma_f32_16x16x32_bf16(af1, bv, acc[nf], 0, 0, 0);
    }
    cur = (cur == 2) ? 0 : cur + 1;
  }

  __syncthreads();
  float* accS = (float*)&Bs[0][0][0][0];
  if (grp == 1) {
#pragma unroll
    for (int nf = 0; nf < 4; ++nf)
      *(f32x4*)&accS[((wq * 64 + l) * 4 + nf) * 4] = acc[nf];
  }
  __syncthreads();
  if (grp == 0) {
#pragma unroll
    for (int nf = 0; nf < 4; ++nf)
      acc[nf] += *(const f32x4*)&accS[((wq * 64 + l) * 4 + nf) * 4];

    const int iw = i0 + wq * 16 + (l >> 4) * 4;
    fx4 sv = *(const fx4*)&smrow[iw];
    float fv[4];
#pragma unroll
    for (int r = 0; r < 4; ++r) fv[r] = (sv[r] == 0.f) ? 0.25f : 0.f;
    if (MODE == 0) {
#pragma unroll
      for (int nf = 0; nf < 4; ++nf) {
        const int ch = h * 64 + nf * 16 + dl;
        const size_t base = ((size_t)(b * Cc + ch)) * Nn + iw;
        fx4 gv = *(const fx4*)&g[base];
        fx4 res;
#pragma unroll
        for (int r = 0; r < 4; ++r) res[r] = gv[r] * (1.f + fv[r]) + acc[nf][r];
        *(fx4*)&out[base] = res;
      }
    } else {
#pragma unroll
      for (int nf = 0; nf < 4; ++nf) {
        const int ch = h * 64 + nf * 16 + dl;
        fx4 gv = *(const fx4*)&g[((size_t)(b * Cc + ch)) * Nn + iw];
#pragma unroll
        for (int r = 0; r < 4; ++r)
          out[((size_t)b * Nn + iw + r) * Cc + ch] = acc[nf][r] + fv[r] * gv[r];
      }
    }
  }
}

// ---------------------------------------------------------------------------
// Fused LayerNorm stats + final residual add, one pass (r17-proven).
// ---------------------------------------------------------------------------
__global__ __launch_bounds__(256) void k_lnfinal(float* __restrict__ io,
                                                 const float* __restrict__ g2,
                                                 const float* __restrict__ lng,
                                                 const float* __restrict__ lnb) {
  __shared__ float gt[32][258];
  const int b = blockIdx.x, i0 = blockIdx.y * 32;
  const int t = threadIdx.x, w = t >> 6, l = t & 63;
  {
    const int n = t & 31, ch = t >> 5;
#pragma unroll 8
    for (int rr = 0; rr < 32; ++rr) {
      int c = rr * 8 + ch;
      gt[n][c] = g2[((size_t)(b * Cc + c)) * Nn + i0 + n];
    }
  }
  __syncthreads();
  const fx4 lngv = *(const fx4*)&lng[l * 4];
  const fx4 lnbv = *(const fx4*)&lnb[l * 4];
#pragma unroll
  for (int r = 0; r < 8; ++r) {
    const int n = r * 4 + w;
    const size_t base = ((size_t)(b * Nn) + i0 + n) * Cc + l * 4;
    fx4 v = *(const fx4*)&io[base];
    float s = v[0] + v[1] + v[2] + v[3];
    float sq = v[0] * v[0] + v[1] * v[1] + v[2] * v[2] + v[3] * v[3];
#pragma unroll
    for (int off = 32; off; off >>= 1) {
      s += __shfl_xor(s, off, 64);
      sq += __shfl_xor(sq, off, 64);
    }
    const float m = s * (1.f / 256.f);
    const float var = sq * (1.f / 256.f) - m * m;
    const float rstd = rsqrtf(fmaxf(var, 0.f) + 1e-6f);
    fx4 gv = *(const fx4*)&gt[n][l * 4];
    fx4 res;
#pragma unroll
    for (int e = 0; e < 4; ++e)
      res[e] = gv[e] + (v[e] - m) * rstd * lngv[e] + lnbv[e];
    *(fx4*)&io[base] = res;
  }
}

// ---------------------------------------------------------------------------
extern "C" void kernel_launch(void* const* d_in, const int* in_sizes, int n_in,
                              void* d_out, int out_size, void* d_ws, size_t ws_size,
                              hipStream_t stream) {
  (void)in_sizes; (void)n_in; (void)out_size; (void)ws_size;
  const float* input = (const float*)d_in[0];
  const float* roi   = (const float*)d_in[1];   // masks_roi [B,N,N]
  const float* sm    = (const float*)d_in[2];   // score_mask [B,N]
  const float* spat  = (const float*)d_in[3];
  const float* W1    = (const float*)d_in[4];
  const float* b1    = (const float*)d_in[5];
  const float* W2    = (const float*)d_in[6];
  const float* b2    = (const float*)d_in[7];
  const float* cw1   = (const float*)d_in[8];
  const float* cb1   = (const float*)d_in[9];
  const float* cw2   = (const float*)d_in[10];
  const float* cb2   = (const float*)d_in[11];
  const float* lng   = (const float*)d_in[12];
  const float* lnb   = (const float*)d_in[13];
  // d_in[14] = node_num: unused — scores[b,i,i]=1 is the strict row max, so
  // every column lands in some row's top-k and the `present` mask is all-ones.

  float* outf = (float*)d_out;
  char* ws = (char*)d_ws;
  const size_t PLANE = (size_t)Bb * Cc * Nn;  // 2M elements
  float* gbuf = (float*)ws;                              // conv out f32, 8MB
  __bf16* gsm = (__bf16*)(ws + PLANE * 4);               // 0.25*sm*g bf16, 4MB
  unsigned long long* roib =
      (unsigned long long*)(ws + PLANE * 4 + PLANE * 2); // 1MB (8192 rows x 128B)
  float* qtb = (float*)((char*)roib + (size_t)Bb * Nn * 128);
  float* ktb = qtb + Bb * Hh * Nn;
  int* cntb = (int*)(ktb + Bb * Hh * Nn);                // 8 ints
  // d_out doubles as scratch: holds out1 [B,C,N] (apply1), then final out.
  float* out1 = outf;

  k_rpgc0<<<dim3(2304), 256, 0, stream>>>(input, cw1, cb1, sm, spat, W1, b1,
                                          gbuf, gsm, qtb, ktb, roi, roib, cntb);
  k_apply7<0><<<dim3(8, 16, 4), 512, 0, stream>>>(gbuf, gsm, qtb, ktb,
                                                  (const unsigned char*)roib, sm,
                                                  cntb, out1);
  k_gconvq1<<<dim3(8, 32), 256, 0, stream>>>(out1, cw2, cb2, sm, spat, W2, b2,
                                             gbuf, gsm, qtb, ktb);
  k_apply7<1><<<dim3(8, 16, 4), 512, 0, stream>>>(gbuf, gsm, qtb, ktb,
                                                  (const unsigned char*)roib, sm,
                                                  cntb, outf);
  k_lnfinal<<<dim3(8, 32), 256, 0, stream>>>(outf, gbuf, lng, lnb);
}